// Round 1
// baseline (798.656 us; speedup 1.0000x reference)
//
#include <hip/hip_runtime.h>
#include <cstdint>

#define M_DIM 16384
#define N_DIM 4096
#define K_DIM 4096

#define BM 128
#define BN 128
#define BK 64

typedef __attribute__((ext_vector_type(4))) int int32x4;

#define GLLD16(g, l)                                              \
  __builtin_amdgcn_global_load_lds(                               \
      (const __attribute__((address_space(1))) void*)(g),         \
      (__attribute__((address_space(3))) void*)(l), 16, 0, 0)

// ---------------------------------------------------------------------------
// Kernel 1: quantize activations  x -> int8 (zero-point kept IN the value;
// corrected later via wsum). 16 floats per thread.
// ---------------------------------------------------------------------------
__global__ void quant_x_kernel(const float* __restrict__ x,
                               const float* __restrict__ sp,
                               const int* __restrict__ zpp,
                               int8_t* __restrict__ qx) {
  const float s = sp[0];
  const int zp = zpp[0];
  const long long t = (long long)blockIdx.x * blockDim.x + threadIdx.x;
  const float4* x4 = (const float4*)x;
  unsigned packed[4];
#pragma unroll
  for (int i = 0; i < 4; i++) {
    float4 v = x4[t * 4 + i];
    int q0 = min(127, max(-128, (int)rintf(v.x / s) + zp));
    int q1 = min(127, max(-128, (int)rintf(v.y / s) + zp));
    int q2 = min(127, max(-128, (int)rintf(v.z / s) + zp));
    int q3 = min(127, max(-128, (int)rintf(v.w / s) + zp));
    packed[i] = (unsigned)(q0 & 255) | ((unsigned)(q1 & 255) << 8) |
                ((unsigned)(q2 & 255) << 16) | ((unsigned)(q3 & 255) << 24);
  }
  int4 outv;
  outv.x = (int)packed[0]; outv.y = (int)packed[1];
  outv.z = (int)packed[2]; outv.w = (int)packed[3];
  ((int4*)qx)[t] = outv;
}

// ---------------------------------------------------------------------------
// Kernel 2: quantize weights (one block per output channel n), compute
// wsum[n] = sum_k qw[n,k], then cs[n] = s*ws[n], off[n] = bias - zp*wsum*cs.
// ---------------------------------------------------------------------------
__global__ void quant_w_kernel(const float* __restrict__ w,
                               const float* __restrict__ wscale,
                               const float* __restrict__ bias,
                               const float* __restrict__ sp,
                               const int* __restrict__ zpp,
                               int8_t* __restrict__ qw,
                               float* __restrict__ cs,
                               float* __restrict__ off) {
  const int n = blockIdx.x;
  const float ws = wscale[n];
  const float s = sp[0];
  const int zp = zpp[0];
  const float4* wr = (const float4*)(w + (size_t)n * K_DIM);
  unsigned* qr = (unsigned*)(qw + (size_t)n * K_DIM);
  int sum = 0;
#pragma unroll
  for (int it = 0; it < K_DIM / (256 * 4); it++) {
    const int idx = it * 256 + threadIdx.x;
    float4 v = wr[idx];
    int q0 = min(127, max(-128, (int)rintf(v.x / ws)));
    int q1 = min(127, max(-128, (int)rintf(v.y / ws)));
    int q2 = min(127, max(-128, (int)rintf(v.z / ws)));
    int q3 = min(127, max(-128, (int)rintf(v.w / ws)));
    sum += q0 + q1 + q2 + q3;
    qr[idx] = (unsigned)(q0 & 255) | ((unsigned)(q1 & 255) << 8) |
              ((unsigned)(q2 & 255) << 16) | ((unsigned)(q3 & 255) << 24);
  }
  __shared__ int red[4];
#pragma unroll
  for (int o = 32; o > 0; o >>= 1) sum += __shfl_down(sum, o, 64);
  if ((threadIdx.x & 63) == 0) red[threadIdx.x >> 6] = sum;
  __syncthreads();
  if (threadIdx.x == 0) {
    const int tot = red[0] + red[1] + red[2] + red[3];
    const float c = s * ws;
    cs[n] = c;
    off[n] = bias[n] - (float)(zp * tot) * c;
  }
}

// ---------------------------------------------------------------------------
// Kernel 3: int8 GEMM, m97 structure. Block = 256 thr = 4 waves.
// Tile 128x128, BK=64 (int8). Each wave: 64x64 = 4x4 tiles of 16x16x64 MFMA.
// LDS chunks (16B) XOR-swizzled: chunk c of row r stored at c ^ ((r>>1)&3)
// so fragment ds_read_b128 is bank-balanced (2 lanes/bank = free).
// ---------------------------------------------------------------------------
__global__ __launch_bounds__(256) void gemm_i8(
    const int8_t* __restrict__ qx, const int8_t* __restrict__ qw,
    const float* __restrict__ cs, const float* __restrict__ off,
    float* __restrict__ out) {
  __shared__ __align__(16) int8_t As[BM * BK];  // 8 KB
  __shared__ __align__(16) int8_t Bs[BN * BK];  // 8 KB

  const int tid = threadIdx.x;
  const int lane = tid & 63;
  const int wave = tid >> 6;  // 0..3
  const int wm = wave >> 1;   // 0..1
  const int wn = wave & 1;    // 0..1

  const int n0 = blockIdx.x * BN;
  const int m0 = blockIdx.y * BM;

  int32x4 acc[4][4] = {};

  // ---- staging addresses (2 A-insts + 2 B-insts per wave, 1 KB each) ----
  const int ci = wave * 2;                    // chunk-pair base (0,2,4,6)
  const int sr0 = (ci + 0) * 16 + (lane >> 2);  // LDS row of inst 0
  const int sr1 = (ci + 1) * 16 + (lane >> 2);  // LDS row of inst 1
  const int sc0 = (lane & 3) ^ ((sr0 >> 1) & 3);  // swizzled source chunk
  const int sc1 = (lane & 3) ^ ((sr1 >> 1) & 3);

  const int8_t* gA0 = qx + (size_t)(m0 + sr0) * K_DIM + sc0 * 16;
  const int8_t* gA1 = qx + (size_t)(m0 + sr1) * K_DIM + sc1 * 16;
  const int8_t* gB0 = qw + (size_t)(n0 + sr0) * K_DIM + sc0 * 16;
  const int8_t* gB1 = qw + (size_t)(n0 + sr1) * K_DIM + sc1 * 16;

  int8_t* ldsA0 = As + (ci + 0) * 1024;
  int8_t* ldsA1 = As + (ci + 1) * 1024;
  int8_t* ldsB0 = Bs + (ci + 0) * 1024;
  int8_t* ldsB1 = Bs + (ci + 1) * 1024;

  // ---- fragment read offsets ----
  const int fr = lane & 15;   // row within 16-tile (m or n)
  const int quad = lane >> 4; // k-chunk index (k = quad*16 + j)
  const int fch = (quad ^ ((fr >> 1) & 3)) * 16;  // swizzled chunk byte off

  int aoff[4], boff[4];
#pragma unroll
  for (int t = 0; t < 4; t++) {
    aoff[t] = (wm * 64 + t * 16 + fr) * BK + fch;
    boff[t] = (wn * 64 + t * 16 + fr) * BK + fch;
  }

  for (int kt = 0; kt < K_DIM; kt += BK) {
    __syncthreads();  // previous iteration's LDS reads complete
    GLLD16(gA0 + kt, ldsA0);
    GLLD16(gA1 + kt, ldsA1);
    GLLD16(gB0 + kt, ldsB0);
    GLLD16(gB1 + kt, ldsB1);
    __syncthreads();  // compiler drains vmcnt(0) before s_barrier

    int32x4 af[4], bf[4];
#pragma unroll
    for (int t = 0; t < 4; t++) {
      af[t] = *(const int32x4*)(As + aoff[t]);
      bf[t] = *(const int32x4*)(Bs + boff[t]);
    }
#pragma unroll
    for (int tm = 0; tm < 4; tm++)
#pragma unroll
      for (int tn = 0; tn < 4; tn++)
        acc[tm][tn] = __builtin_amdgcn_mfma_i32_16x16x64_i8(
            af[tm], bf[tn], acc[tm][tn], 0, 0, 0);
  }

  // ---- epilogue: out = acc * cs[col] + off[col] ----
#pragma unroll
  for (int tn = 0; tn < 4; tn++) {
    const int col = n0 + wn * 64 + tn * 16 + fr;
    const float c = cs[col];
    const float o = off[col];
#pragma unroll
    for (int tm = 0; tm < 4; tm++) {
      const int rowb = m0 + wm * 64 + tm * 16 + quad * 4;
#pragma unroll
      for (int r = 0; r < 4; r++) {
        out[(size_t)(rowb + r) * N_DIM + col] = (float)acc[tm][tn][r] * c + o;
      }
    }
  }
}

// ---------------------------------------------------------------------------
extern "C" void kernel_launch(void* const* d_in, const int* in_sizes, int n_in,
                              void* d_out, int out_size, void* d_ws,
                              size_t ws_size, hipStream_t stream) {
  const float* x = (const float*)d_in[0];
  const float* w = (const float*)d_in[1];
  const float* bias = (const float*)d_in[2];
  const float* act_scale = (const float*)d_in[3];
  const int* zp = (const int*)d_in[4];
  const float* wscale = (const float*)d_in[5];
  float* out = (float*)d_out;

  int8_t* qx = (int8_t*)d_ws;                          // 64 MB
  int8_t* qw = qx + (size_t)M_DIM * K_DIM;             // 16 MB
  float* cs = (float*)(qw + (size_t)N_DIM * K_DIM);    // 16 KB
  float* off = cs + N_DIM;                             // 16 KB

  // 67108864 elems / 16 per thread / 256 per block = 16384 blocks
  quant_x_kernel<<<16384, 256, 0, stream>>>(x, act_scale, zp, qx);
  quant_w_kernel<<<N_DIM, 256, 0, stream>>>(w, wscale, bias, act_scale, zp,
                                            qw, cs, off);
  gemm_i8<<<dim3(N_DIM / BN, M_DIM / BM), 256, 0, stream>>>(qx, qw, cs, off,
                                                            out);
}